// Round 5
// baseline (11405.574 us; speedup 1.0000x reference)
//
#include <hip/hip_runtime.h>

#define DIN   784
#define DPAD  800
#define NLAT  1024
#define BM    64
#define NITER 48       // 1 analytic step (u1 = 0.1*b) + 48 full steps = 49 steps

typedef __attribute__((ext_vector_type(8))) short  short8;
typedef __attribute__((ext_vector_type(4))) float  f32x4;
typedef __attribute__((ext_vector_type(4))) unsigned int u32x4;

__device__ __forceinline__ unsigned short f2bf(float f) {
    unsigned int u = __builtin_bit_cast(unsigned int, f);
    u += 0x7fffu + ((u >> 16) & 1u);     // RNE
    return (unsigned short)(u >> 16);
}
__device__ __forceinline__ unsigned int pk2(float a, float b) {
    return (unsigned int)f2bf(a) | ((unsigned int)f2bf(b) << 16);
}
__device__ __forceinline__ float bf2f_lo(unsigned int p) { return __builtin_bit_cast(float, p << 16); }
__device__ __forceinline__ float bf2f_hi(unsigned int p) { return __builtin_bit_cast(float, p & 0xffff0000u); }

// ---------------- prep kernels ----------------

__global__ void convert_w_kernel(const float* __restrict__ w, unsigned short* __restrict__ wbf) {
    int i = blockIdx.x * 256 + threadIdx.x;   // grid covers exactly 784*1024
    wbf[i] = f2bf(w[i]);
}

// wT[l][d] = w[d][l], padded to DPAD cols with zeros (for b = x@w B-fragments)
__global__ void transpose_pad_kernel(const float* __restrict__ w, unsigned short* __restrict__ wT) {
    __shared__ float tile[32][33];
    int d0 = blockIdx.x * 32;
    int l0 = blockIdx.y * 32;
    int tx = threadIdx.x, ty = threadIdx.y;
    int d = d0 + ty;
    tile[ty][tx] = (d < DIN) ? w[(size_t)d * NLAT + l0 + tx] : 0.f;
    __syncthreads();
    wT[(size_t)(l0 + ty) * DPAD + d0 + tx] = f2bf(tile[tx][ty]);
}

// g = w^T w - I, bf16, row-major [1024][1024] (symmetric)
__global__ void gram_kernel(const float* __restrict__ w, unsigned short* __restrict__ g) {
    __shared__ float Wk[32][33];
    __shared__ float Wl[32][33];
    int k0 = blockIdx.x * 32, l0 = blockIdx.y * 32;
    int t = threadIdx.x;
    int c = t & 31, r8 = t >> 5;
    float acc[4] = {0.f, 0.f, 0.f, 0.f};
    for (int d0 = 0; d0 < DPAD; d0 += 32) {
        __syncthreads();
        #pragma unroll
        for (int rr = 0; rr < 4; ++rr) {
            int d = d0 + r8 + rr * 8;
            float vk = 0.f, vl = 0.f;
            if (d < DIN) {
                vk = w[(size_t)d * NLAT + k0 + c];
                vl = w[(size_t)d * NLAT + l0 + c];
            }
            Wk[r8 + rr * 8][c] = vk;
            Wl[r8 + rr * 8][c] = vl;
        }
        __syncthreads();
        #pragma unroll
        for (int dd = 0; dd < 32; ++dd) {
            float bl = Wl[dd][c];
            #pragma unroll
            for (int rr = 0; rr < 4; ++rr)
                acc[rr] += Wk[dd][r8 + rr * 8] * bl;
        }
    }
    #pragma unroll
    for (int rr = 0; rr < 4; ++rr) {
        int kr = k0 + r8 + rr * 8;
        int lc = l0 + c;
        float v = acc[rr] - ((kr == lc) ? 1.f : 0.f);
        g[(size_t)kr * NLAT + lc] = f2bf(v);
    }
}

// ---------------- fused main kernel ----------------
// 256 blocks x 512 threads (8 waves, 1 block/CU). Block owns 64 rows.
// Wave wv owns latent cols [wv*128, wv*128+128). Invariant: u = -0.1 * acc.
// b (packed bf16) lives in THIS BLOCK'S OWN out region: dwords [bid*50176, +32768)
// -- recon overwrites it only after the last b read (barrier-ordered, same block).
// a_lds: logical a[64][1024] bf16, byte(row,col) = row*2048 + ((col/8 ^ (row&7))*16) + (col%8)*2.
// Register budget: acc = 128 AGPR; everything else must stay <= ~128 VGPR (8-wave
// block residency cap = 256 unified regs/wave).

__global__ __launch_bounds__(512, 2) void lca_main_kernel(
    const float* __restrict__ x,
    const unsigned short* __restrict__ g,
    const unsigned short* __restrict__ wbf,
    const unsigned short* __restrict__ wT,
    float* __restrict__ out)
{
    extern __shared__ char smem[];
    char* a_lds = smem;                                   // 64 * 2048 B (swizzled)
    unsigned short* x_lds = (unsigned short*)(smem + BM * 2048);  // [2][64][40] bf16

    const int tid  = threadIdx.x;
    const int lane = tid & 63;
    const int wv   = tid >> 6;          // 0..7
    const int l15  = lane & 15;
    const int l7   = lane & 7;
    const int lg   = lane >> 4;         // 0..3
    const int rowbase = blockIdx.x * BM;
    const int wcol = wv * 128;

    // block's own out region: 50176 dwords = 12544 u32x4; scratch uses first 8192
    u32x4* bs4 = (u32x4*)out;
    const size_t bsbase = (size_t)blockIdx.x * 12544 + tid;

    f32x4 acc[4][8];
    #pragma unroll
    for (int mt = 0; mt < 4; ++mt)
        #pragma unroll
        for (int nt = 0; nt < 8; ++nt)
            acc[mt][nt] = (f32x4){0.f, 0.f, 0.f, 0.f};

    // ---- phase 0: acc <- b = x @ w (K padded 784->800, 25 chunks of 32) ----
    const int srow = tid >> 3;   // 0..63
    const int sq   = tid & 7;    // 0..7
    {
        int k = sq * 4;
        f32x4 v = (f32x4){0.f, 0.f, 0.f, 0.f};
        if (k < DIN) v = __builtin_nontemporal_load((const f32x4*)(x + (size_t)(rowbase + srow) * DIN + k));
        unsigned short* dst = x_lds + srow * 40 + sq * 4;
        *(unsigned int*)(dst)     = pk2(v.x, v.y);
        *(unsigned int*)(dst + 2) = pk2(v.z, v.w);
    }
    __syncthreads();
    for (int kc = 0; kc < 25; ++kc) {
        if (kc < 24) {
            int k = (kc + 1) * 32 + sq * 4;
            f32x4 v = (f32x4){0.f, 0.f, 0.f, 0.f};
            if (k < DIN) v = __builtin_nontemporal_load((const f32x4*)(x + (size_t)(rowbase + srow) * DIN + k));
            unsigned short* dst = x_lds + ((kc + 1) & 1) * (BM * 40) + srow * 40 + sq * 4;
            *(unsigned int*)(dst)     = pk2(v.x, v.y);
            *(unsigned int*)(dst + 2) = pk2(v.z, v.w);
        }
        const int buf = kc & 1;
        short8 af[4];
        #pragma unroll
        for (int mt = 0; mt < 4; ++mt)
            af[mt] = *(const short8*)(x_lds + buf * (BM * 40) + (mt * 16 + l15) * 40 + lg * 8);
        #pragma unroll
        for (int nt = 0; nt < 8; ++nt) {
            short8 bfr = *(const short8*)(wT + (size_t)(wcol + nt * 16 + l15) * DPAD + kc * 32 + lg * 8);
            #pragma unroll
            for (int mt = 0; mt < 4; ++mt)
                acc[mt][nt] = __builtin_amdgcn_mfma_f32_16x16x32_bf16(af[mt], bfr, acc[mt][nt], 0, 0, 0);
        }
        __syncthreads();
    }

    // ---- stash b (packed bf16) into own-region scratch; set acc = -b ----
    #pragma unroll
    for (int d4 = 0; d4 < 16; ++d4) {
        int p0 = d4 * 2, p1 = d4 * 2 + 1;
        u32x4 v;
        v.x = pk2(acc[p0 >> 3][p0 & 7][0], acc[p0 >> 3][p0 & 7][1]);
        v.y = pk2(acc[p0 >> 3][p0 & 7][2], acc[p0 >> 3][p0 & 7][3]);
        v.z = pk2(acc[p1 >> 3][p1 & 7][0], acc[p1 >> 3][p1 & 7][1]);
        v.w = pk2(acc[p1 >> 3][p1 & 7][2], acc[p1 >> 3][p1 & 7][3]);
        __builtin_nontemporal_store(v, bs4 + bsbase + d4 * 512);
    }
    #pragma unroll
    for (int mt = 0; mt < 4; ++mt)
        #pragma unroll
        for (int nt = 0; nt < 8; ++nt)
            acc[mt][nt] = -acc[mt][nt];

    // g addressing: uniform SGPR panel base (readfirstlane) + one VGPR voffset;
    // kc*64 folds into the 13-bit imm offset -> zero address VALU in the K-loop.
    const char* gpan = (const char*)g + (size_t)__builtin_amdgcn_readfirstlane(wv * (128 * 2048));
    const int gvoff = l15 * 2048 + lg * 16;

    auto LDAF = [&](short8 (&af)[4], int kc) {
        int colb = ((kc * 4 + lg) ^ l7) << 4;
        #pragma unroll
        for (int mt = 0; mt < 4; ++mt)
            af[mt] = *(const short8*)(a_lds + (mt * 16 + l15) * 2048 + colb);
    };
    auto LDG = [&](short8 (&bfr)[8], int kc) {
        #pragma unroll
        for (int j = 0; j < 8; ++j)
            bfr[j] = *(const short8*)(gpan + j * 32768 + gvoff + kc * 64);
    };
    auto MM = [&](short8 (&af)[4], short8 (&bfr)[8]) {
        #pragma unroll
        for (int j = 0; j < 8; ++j)
            #pragma unroll
            for (int mt = 0; mt < 4; ++mt)
                acc[mt][j] = __builtin_amdgcn_mfma_f32_16x16x32_bf16(af[mt], bfr[j], acc[mt][j], 0, 0, 0);
    };
    auto THRW = [&]() {
        #pragma unroll
        for (int mt = 0; mt < 4; ++mt)
            #pragma unroll
            for (int nt = 0; nt < 8; ++nt) {
                int chunkbase = (wcol >> 3) + nt * 2 + (l15 >> 3);
                #pragma unroll
                for (int r = 0; r < 4; ++r) {
                    int row = mt * 16 + lg * 4 + r;
                    float a = fmaxf(fmaf(-0.1f, acc[mt][nt][r], -0.3f), 0.f);
                    *(unsigned short*)(a_lds + row * 2048 + ((chunkbase ^ (row & 7)) << 4) + l7 * 2) = f2bf(a);
                }
            }
    };

    short8 afA[4], afB[4], gA[8], gBf[8];

    // ---- 48 full steps: A' = 0.9*A - b + threshold(-0.1*A) @ g ----
    #pragma unroll 1
    for (int it = 0; it < NITER; ++it) {
        __syncthreads();   // all waves done reading prior a_lds
        // stream b back (nontemporal, own block's region); latency hidden under THRW
        u32x4 br[16];
        #pragma unroll
        for (int d4 = 0; d4 < 16; ++d4)
            br[d4] = __builtin_nontemporal_load(bs4 + bsbase + d4 * 512);
        THRW();
        __syncthreads();
        // C_init = 0.9*A - b
        #pragma unroll
        for (int mt = 0; mt < 4; ++mt)
            #pragma unroll
            for (int nt = 0; nt < 8; ++nt) {
                int p = mt * 8 + nt;
                unsigned int w0 = (p & 1) ? br[p >> 1].z : br[p >> 1].x;
                unsigned int w1 = (p & 1) ? br[p >> 1].w : br[p >> 1].y;
                acc[mt][nt][0] = fmaf(0.9f, acc[mt][nt][0], -bf2f_lo(w0));
                acc[mt][nt][1] = fmaf(0.9f, acc[mt][nt][1], -bf2f_hi(w0));
                acc[mt][nt][2] = fmaf(0.9f, acc[mt][nt][2], -bf2f_lo(w1));
                acc[mt][nt][3] = fmaf(0.9f, acc[mt][nt][3], -bf2f_hi(w1));
            }
        // pipelined K-loop (2-stage; peak ~116 VGPR incl. af/g double-buffer)
        LDAF(afA, 0); LDG(gA, 0);
        #pragma unroll
        for (int kc = 0; kc < 32; kc += 2) {
            LDAF(afB, kc + 1); LDG(gBf, kc + 1);
            MM(afA, gA);
            if (kc + 2 < 32) { LDAF(afA, kc + 2); LDG(gA, kc + 2); }
            MM(afB, gBf);
        }
    }

    // ---- final a, then recon = a @ w^T ----
    __syncthreads();
    THRW();
    __syncthreads();
    const int nt0 = wv * 6;
    const int ntn = (wv == 7) ? 7 : 6;     // 7*6 + 7 = 49 tiles of 16 = 784 cols
    for (int t = 0; t < ntn; ++t) {
        int nt = nt0 + t;
        f32x4 racc[4];
        #pragma unroll
        for (int mt = 0; mt < 4; ++mt) racc[mt] = (f32x4){0.f, 0.f, 0.f, 0.f};
        for (int kc = 0; kc < 32; ++kc) {
            short8 af[4];
            LDAF(af, kc);
            short8 bw = *(const short8*)(wbf + (size_t)(nt * 16 + l15) * NLAT + kc * 32 + lg * 8);
            #pragma unroll
            for (int mt = 0; mt < 4; ++mt)
                racc[mt] = __builtin_amdgcn_mfma_f32_16x16x32_bf16(af[mt], bw, racc[mt], 0, 0, 0);
        }
        #pragma unroll
        for (int mt = 0; mt < 4; ++mt)
            #pragma unroll
            for (int r = 0; r < 4; ++r)
                __builtin_nontemporal_store(racc[mt][r],
                    out + (size_t)(rowbase + mt * 16 + lg * 4 + r) * DIN + nt * 16 + l15);
    }
}

// ---------------- launch ----------------

extern "C" void kernel_launch(void* const* d_in, const int* in_sizes, int n_in,
                              void* d_out, int out_size, void* d_ws, size_t ws_size,
                              hipStream_t stream) {
    const float* x = (const float*)d_in[0];
    const float* w = (const float*)d_in[1];
    float* out = (float*)d_out;
    char* ws = (char*)d_ws;

    unsigned short* g   = (unsigned short*)(ws);                                  // 2 MB
    unsigned short* wbf = (unsigned short*)(ws + (2u << 20));                     // 784*1024*2
    unsigned short* wT  = (unsigned short*)(ws + (2u << 20) + DIN * NLAT * 2);    // 1024*800*2

    convert_w_kernel<<<3136, 256, 0, stream>>>(w, wbf);
    transpose_pad_kernel<<<dim3(25, 32), dim3(32, 32), 0, stream>>>(w, wT);
    gram_kernel<<<dim3(32, 32), 256, 0, stream>>>(w, g);

    const int smem_bytes = BM * 2048 + 2 * BM * 40 * 2;   // 131072 + 10240 = 141312
    (void)hipFuncSetAttribute((const void*)lca_main_kernel,
                        hipFuncAttributeMaxDynamicSharedMemorySize, smem_bytes);
    lca_main_kernel<<<256, 512, smem_bytes, stream>>>(x, g, wbf, wT, out);
}

// Round 6
// 10256.832 us; speedup vs baseline: 1.1120x; 1.1120x over previous
//
#include <hip/hip_runtime.h>

#define DIN   784
#define DPAD  800
#define NLAT  1024
#define BM    64
#define NITER 48       // 1 analytic step (u1 = 0.1*b) + 48 full steps = 49 steps

typedef __attribute__((ext_vector_type(8))) short  short8;
typedef __attribute__((ext_vector_type(4))) float  f32x4;

__device__ __forceinline__ unsigned short f2bf(float f) {
    unsigned int u = __builtin_bit_cast(unsigned int, f);
    u += 0x7fffu + ((u >> 16) & 1u);     // RNE
    return (unsigned short)(u >> 16);
}
__device__ __forceinline__ unsigned int pk2(float a, float b) {
    return (unsigned int)f2bf(a) | ((unsigned int)f2bf(b) << 16);
}
__device__ __forceinline__ float bf2f_lo(unsigned int p) { return __builtin_bit_cast(float, p << 16); }
__device__ __forceinline__ float bf2f_hi(unsigned int p) { return __builtin_bit_cast(float, p & 0xffff0000u); }

// ---------------- prep kernels ----------------

__global__ void convert_w_kernel(const float* __restrict__ w, unsigned short* __restrict__ wbf) {
    int i = blockIdx.x * 256 + threadIdx.x;   // grid covers exactly 784*1024
    wbf[i] = f2bf(w[i]);
}

// wT[l][d] = w[d][l], padded to DPAD cols with zeros (for b = x@w B-fragments)
__global__ void transpose_pad_kernel(const float* __restrict__ w, unsigned short* __restrict__ wT) {
    __shared__ float tile[32][33];
    int d0 = blockIdx.x * 32;
    int l0 = blockIdx.y * 32;
    int tx = threadIdx.x, ty = threadIdx.y;
    int d = d0 + ty;
    tile[ty][tx] = (d < DIN) ? w[(size_t)d * NLAT + l0 + tx] : 0.f;
    __syncthreads();
    wT[(size_t)(l0 + ty) * DPAD + d0 + tx] = f2bf(tile[tx][ty]);
}

// g = w^T w - I, bf16, row-major [1024][1024] (symmetric)
__global__ void gram_kernel(const float* __restrict__ w, unsigned short* __restrict__ g) {
    __shared__ float Wk[32][33];
    __shared__ float Wl[32][33];
    int k0 = blockIdx.x * 32, l0 = blockIdx.y * 32;
    int t = threadIdx.x;
    int c = t & 31, r8 = t >> 5;
    float acc[4] = {0.f, 0.f, 0.f, 0.f};
    for (int d0 = 0; d0 < DPAD; d0 += 32) {
        __syncthreads();
        #pragma unroll
        for (int rr = 0; rr < 4; ++rr) {
            int d = d0 + r8 + rr * 8;
            float vk = 0.f, vl = 0.f;
            if (d < DIN) {
                vk = w[(size_t)d * NLAT + k0 + c];
                vl = w[(size_t)d * NLAT + l0 + c];
            }
            Wk[r8 + rr * 8][c] = vk;
            Wl[r8 + rr * 8][c] = vl;
        }
        __syncthreads();
        #pragma unroll
        for (int dd = 0; dd < 32; ++dd) {
            float bl = Wl[dd][c];
            #pragma unroll
            for (int rr = 0; rr < 4; ++rr)
                acc[rr] += Wk[dd][r8 + rr * 8] * bl;
        }
    }
    #pragma unroll
    for (int rr = 0; rr < 4; ++rr) {
        int kr = k0 + r8 + rr * 8;
        int lc = l0 + c;
        float v = acc[rr] - ((kr == lc) ? 1.f : 0.f);
        g[(size_t)kr * NLAT + lc] = f2bf(v);
    }
}

// ---------------- fused main kernel ----------------
// 256 blocks x 512 threads (8 waves, 1 block/CU = 2 waves/SIMD). Block owns 64 rows.
// Wave wv owns latent cols [wv*128, wv*128+128). Invariant: u = -0.1 * acc.
// Register budget per wave (2 waves/SIMD => 256 unified regs):
//   acc 128 AGPR  +  bpk 64 + af 16 + gfr 32 + addr ~10 = ~122 VGPR.  NO spills.
// b never leaves registers; d_out is written only by the final recon.
// a_lds: logical a[64][1024] bf16, byte(row,col) = row*2048 + ((col/8 ^ (row&7))*16) + (col%8)*2.

__global__ __launch_bounds__(512, 2) void lca_main_kernel(
    const float* __restrict__ x,
    const unsigned short* __restrict__ g,
    const unsigned short* __restrict__ wbf,
    const unsigned short* __restrict__ wT,
    float* __restrict__ out)
{
    extern __shared__ char smem[];
    char* a_lds = smem;                                   // 64 * 2048 B (swizzled)
    unsigned short* x_lds = (unsigned short*)(smem + BM * 2048);  // [2][64][40] bf16

    const int tid  = threadIdx.x;
    const int lane = tid & 63;
    const int wv   = tid >> 6;          // 0..7
    const int l15  = lane & 15;
    const int l7   = lane & 7;
    const int lg   = lane >> 4;         // 0..3
    const int rowbase = blockIdx.x * BM;
    const int wcol = wv * 128;

    f32x4 acc[4][8];
    #pragma unroll
    for (int mt = 0; mt < 4; ++mt)
        #pragma unroll
        for (int nt = 0; nt < 8; ++nt)
            acc[mt][nt] = (f32x4){0.f, 0.f, 0.f, 0.f};

    // ---- phase 0: acc <- b = x @ w (K padded 784->800, 25 chunks of 32) ----
    const int srow = tid >> 3;   // 0..63
    const int sq   = tid & 7;    // 0..7
    {
        int k = sq * 4;
        f32x4 v = (f32x4){0.f, 0.f, 0.f, 0.f};
        if (k < DIN) v = __builtin_nontemporal_load((const f32x4*)(x + (size_t)(rowbase + srow) * DIN + k));
        unsigned short* dst = x_lds + srow * 40 + sq * 4;
        *(unsigned int*)(dst)     = pk2(v.x, v.y);
        *(unsigned int*)(dst + 2) = pk2(v.z, v.w);
    }
    __syncthreads();
    for (int kc = 0; kc < 25; ++kc) {
        if (kc < 24) {
            int k = (kc + 1) * 32 + sq * 4;
            f32x4 v = (f32x4){0.f, 0.f, 0.f, 0.f};
            if (k < DIN) v = __builtin_nontemporal_load((const f32x4*)(x + (size_t)(rowbase + srow) * DIN + k));
            unsigned short* dst = x_lds + ((kc + 1) & 1) * (BM * 40) + srow * 40 + sq * 4;
            *(unsigned int*)(dst)     = pk2(v.x, v.y);
            *(unsigned int*)(dst + 2) = pk2(v.z, v.w);
        }
        const int buf = kc & 1;
        short8 af[4];
        #pragma unroll
        for (int mt = 0; mt < 4; ++mt)
            af[mt] = *(const short8*)(x_lds + buf * (BM * 40) + (mt * 16 + l15) * 40 + lg * 8);
        #pragma unroll
        for (int nt = 0; nt < 8; ++nt) {
            short8 bfr = *(const short8*)(wT + (size_t)(wcol + nt * 16 + l15) * DPAD + kc * 32 + lg * 8);
            #pragma unroll
            for (int mt = 0; mt < 4; ++mt)
                acc[mt][nt] = __builtin_amdgcn_mfma_f32_16x16x32_bf16(af[mt], bfr, acc[mt][nt], 0, 0, 0);
        }
        __syncthreads();
    }

    // ---- pack b into registers (bf16 pairs, 64 VGPR); set acc = -b ----
    unsigned int bpk[4][8][2];
    #pragma unroll
    for (int mt = 0; mt < 4; ++mt)
        #pragma unroll
        for (int nt = 0; nt < 8; ++nt) {
            bpk[mt][nt][0] = pk2(acc[mt][nt][0], acc[mt][nt][1]);
            bpk[mt][nt][1] = pk2(acc[mt][nt][2], acc[mt][nt][3]);
            acc[mt][nt] = -acc[mt][nt];
        }

    // g addressing: uniform SGPR panel base (readfirstlane) + one VGPR voffset;
    // kc*64 folds into the imm offset -> zero address VALU in the K-loop.
    const char* gpan = (const char*)g + (size_t)__builtin_amdgcn_readfirstlane(wv * (128 * 2048));
    const int gvoff = l15 * 2048 + lg * 16;

    auto LDAF = [&](short8 (&af)[4], int kc) {
        int colb = ((kc * 4 + lg) ^ l7) << 4;
        #pragma unroll
        for (int mt = 0; mt < 4; ++mt)
            af[mt] = *(const short8*)(a_lds + (mt * 16 + l15) * 2048 + colb);
    };
    auto LDG = [&](short8 (&bfr)[8], int kc) {
        #pragma unroll
        for (int j = 0; j < 8; ++j)
            bfr[j] = *(const short8*)(gpan + j * 32768 + gvoff + kc * 64);
    };
    auto MM = [&](short8 (&af)[4], short8 (&bfr)[8]) {
        #pragma unroll
        for (int j = 0; j < 8; ++j)
            #pragma unroll
            for (int mt = 0; mt < 4; ++mt)
                acc[mt][j] = __builtin_amdgcn_mfma_f32_16x16x32_bf16(af[mt], bfr[j], acc[mt][j], 0, 0, 0);
    };
    auto THRW = [&]() {
        #pragma unroll
        for (int mt = 0; mt < 4; ++mt)
            #pragma unroll
            for (int nt = 0; nt < 8; ++nt) {
                int chunkbase = (wcol >> 3) + nt * 2 + (l15 >> 3);
                #pragma unroll
                for (int r = 0; r < 4; ++r) {
                    int row = mt * 16 + lg * 4 + r;
                    float a = fmaxf(fmaf(-0.1f, acc[mt][nt][r], -0.3f), 0.f);
                    *(unsigned short*)(a_lds + row * 2048 + ((chunkbase ^ (row & 7)) << 4) + l7 * 2) = f2bf(a);
                }
            }
    };

    // ---- 48 full steps: A' = 0.9*A - b + threshold(-0.1*A) @ g ----
    #pragma unroll 1
    for (int it = 0; it < NITER; ++it) {
        __syncthreads();   // all waves done reading prior a_lds
        THRW();
        __syncthreads();
        // C_init = 0.9*A - b  (b unpacked from registers)
        #pragma unroll
        for (int mt = 0; mt < 4; ++mt)
            #pragma unroll
            for (int nt = 0; nt < 8; ++nt) {
                acc[mt][nt][0] = fmaf(0.9f, acc[mt][nt][0], -bf2f_lo(bpk[mt][nt][0]));
                acc[mt][nt][1] = fmaf(0.9f, acc[mt][nt][1], -bf2f_hi(bpk[mt][nt][0]));
                acc[mt][nt][2] = fmaf(0.9f, acc[mt][nt][2], -bf2f_lo(bpk[mt][nt][1]));
                acc[mt][nt][3] = fmaf(0.9f, acc[mt][nt][3], -bf2f_hi(bpk[mt][nt][1]));
            }
        // single-buffered K-loop; latency covered by sibling wave on the SIMD
        #pragma unroll
        for (int kc = 0; kc < 32; ++kc) {
            short8 af[4], gfr[8];
            LDG(gfr, kc);
            LDAF(af, kc);
            MM(af, gfr);
        }
    }

    // ---- final a, then recon = a @ w^T ----
    __syncthreads();
    THRW();
    __syncthreads();
    const int nt0 = wv * 6;
    const int ntn = (wv == 7) ? 7 : 6;     // 7*6 + 7 = 49 tiles of 16 = 784 cols
    for (int t = 0; t < ntn; ++t) {
        int nt = nt0 + t;
        f32x4 racc[4];
        #pragma unroll
        for (int mt = 0; mt < 4; ++mt) racc[mt] = (f32x4){0.f, 0.f, 0.f, 0.f};
        for (int kc = 0; kc < 32; ++kc) {
            short8 af[4];
            LDAF(af, kc);
            short8 bw = *(const short8*)(wbf + (size_t)(nt * 16 + l15) * NLAT + kc * 32 + lg * 8);
            #pragma unroll
            for (int mt = 0; mt < 4; ++mt)
                racc[mt] = __builtin_amdgcn_mfma_f32_16x16x32_bf16(af[mt], bw, racc[mt], 0, 0, 0);
        }
        #pragma unroll
        for (int mt = 0; mt < 4; ++mt)
            #pragma unroll
            for (int r = 0; r < 4; ++r)
                __builtin_nontemporal_store(racc[mt][r],
                    out + (size_t)(rowbase + mt * 16 + lg * 4 + r) * DIN + nt * 16 + l15);
    }
}

// ---------------- launch ----------------

extern "C" void kernel_launch(void* const* d_in, const int* in_sizes, int n_in,
                              void* d_out, int out_size, void* d_ws, size_t ws_size,
                              hipStream_t stream) {
    const float* x = (const float*)d_in[0];
    const float* w = (const float*)d_in[1];
    float* out = (float*)d_out;
    char* ws = (char*)d_ws;

    unsigned short* g   = (unsigned short*)(ws);                                  // 2 MB
    unsigned short* wbf = (unsigned short*)(ws + (2u << 20));                     // 784*1024*2
    unsigned short* wT  = (unsigned short*)(ws + (2u << 20) + DIN * NLAT * 2);    // 1024*800*2

    convert_w_kernel<<<3136, 256, 0, stream>>>(w, wbf);
    transpose_pad_kernel<<<dim3(25, 32), dim3(32, 32), 0, stream>>>(w, wT);
    gram_kernel<<<dim3(32, 32), 256, 0, stream>>>(w, g);

    const int smem_bytes = BM * 2048 + 2 * BM * 40 * 2;   // 131072 + 10240 = 141312
    (void)hipFuncSetAttribute((const void*)lca_main_kernel,
                        hipFuncAttributeMaxDynamicSharedMemorySize, smem_bytes);
    lca_main_kernel<<<256, 512, smem_bytes, stream>>>(x, g, wbf, wT, out);
}